// Round 2
// baseline (3779.483 us; speedup 1.0000x reference)
//
#include <hip/hip_runtime.h>

#define NN 4096
#define NPOINTS 1024
#define NSAMP 32
#define MROWS (16*NPOINTS*NSAMP)      // 524288
#define OUT2_OFF (16*NPOINTS*3)       // 49152
#define EPSF 1e-5f
#define RPB 128                       // rows per stats block
#define NBLK 4096                     // stats blocks (NBLK*RPB == MROWS)

// ---------- bf16 helpers ----------
__device__ __forceinline__ float bflo(unsigned int u){ union{unsigned int i; float f;} v; v.i = u << 16; return v.f; }
__device__ __forceinline__ float bfhi(unsigned int u){ union{unsigned int i; float f;} v; v.i = u & 0xffff0000u; return v.f; }
__device__ __forceinline__ unsigned short f2bf(float f){
  union{float f; unsigned int i;} v; v.f = f;
  unsigned int r = v.i + 0x7fffu + ((v.i >> 16) & 1u);
  return (unsigned short)(r >> 16);
}

// ---------- FPS: one block per batch, bit-exact (no FMA), first-occurrence argmax ----------
__global__ __launch_bounds__(512) void k_fps(const float* __restrict__ xyz,
    float* __restrict__ nxyz, float* __restrict__ out){
  __shared__ float xs[NN], ys[NN], zs[NN];
  __shared__ float red_v[8];
  __shared__ int   red_i[8];
  __shared__ int   s_cur;
  const int b = blockIdx.x, t = threadIdx.x;
  const float* xb = xyz + (size_t)b*NN*3;
  for (int j = t; j < NN; j += 512){
    xs[j] = xb[j*3+0]; ys[j] = xb[j*3+1]; zs[j] = xb[j*3+2];
  }
  __syncthreads();
  float px[8], py[8], pz[8], pd[8];
  #pragma unroll
  for (int j=0;j<8;j++){ int i=j*512+t; px[j]=xs[i]; py[j]=ys[i]; pz[j]=zs[i]; pd[j]=1e10f; }
  int cur = 0;
  const int lane = t & 63, wv = t >> 6;
  for (int it=0; it<NPOINTS; ++it){
    float lx = xs[cur], ly = ys[cur], lz = zs[cur];
    if (t == 0){
      int o = (b*NPOINTS + it)*3;
      nxyz[o]=lx; nxyz[o+1]=ly; nxyz[o+2]=lz;
      out[o]=lx;  out[o+1]=ly;  out[o+2]=lz;
    }
    float bv = -1.0f; int bi = 0;
    #pragma unroll
    for (int j=0;j<8;j++){
      float dx = __fsub_rn(px[j], lx);
      float dy = __fsub_rn(py[j], ly);
      float dz = __fsub_rn(pz[j], lz);
      float d  = __fadd_rn(__fadd_rn(__fmul_rn(dx,dx), __fmul_rn(dy,dy)), __fmul_rn(dz,dz));
      float nd = fminf(pd[j], d);
      pd[j] = nd;
      if (nd > bv){ bv = nd; bi = j*512 + t; }   // ascending per-thread idx -> first occurrence
    }
    #pragma unroll
    for (int off=32; off>=1; off>>=1){
      float ov = __shfl_xor(bv, off, 64);
      int   oi = __shfl_xor(bi, off, 64);
      if (ov > bv || (ov == bv && oi < bi)){ bv = ov; bi = oi; }
    }
    if (lane == 0){ red_v[wv] = bv; red_i[wv] = bi; }
    __syncthreads();
    if (t < 64){
      float v2 = (t < 8) ? red_v[t] : -1.0f;
      int   i2 = (t < 8) ? red_i[t] : 0;
      #pragma unroll
      for (int off=4; off>=1; off>>=1){
        float ov = __shfl_xor(v2, off, 64);
        int   oi = __shfl_xor(i2, off, 64);
        if (ov > v2 || (ov == v2 && oi < i2)){ v2 = ov; i2 = oi; }
      }
      if (t == 0) s_cur = i2;
    }
    __syncthreads();
    cur = s_cur;
  }
}

// ---------- Ball query: first-32 in-ball indices; R2 = f32(0.04) exactly ----------
__global__ __launch_bounds__(256) void k_ball(const float* __restrict__ xyz,
    const float* __restrict__ nxyz, int* __restrict__ ball_idx){
  const int bi = blockIdx.x;          // 64 blocks
  const int b = bi >> 2;
  const int p = ((bi & 3) << 8) + threadIdx.x;
  const float* xb = xyz + (size_t)b*NN*3;
  const int co = (b*NPOINTS + p)*3;
  const float cx = nxyz[co], cy = nxyz[co+1], cz = nxyz[co+2];
  const int base = (b*NPOINTS + p)*NSAMP;
  const float R2 = 0.04f;
  int cnt = 0, first = 0;
  for (int i = 0; i < NN; ++i){
    float lx = xb[i*3+0], ly = xb[i*3+1], lz = xb[i*3+2];   // wave-uniform -> s_load
    float dx = __fsub_rn(cx, lx);
    float dy = __fsub_rn(cy, ly);
    float dz = __fsub_rn(cz, lz);
    float d2 = __fadd_rn(__fadd_rn(__fmul_rn(dx,dx), __fmul_rn(dy,dy)), __fmul_rn(dz,dz));
    if (d2 < R2 && cnt < NSAMP){
      ball_idx[base + cnt] = i;
      if (cnt == 0) first = i;
      cnt++;
    }
    if ((i & 255) == 255){
      if (__ballot(cnt < NSAMP) == 0ULL) break;
    }
  }
  for (int k = cnt; k < NSAMP; ++k) ball_idx[base + k] = first;
}

// ---------- weight transposes: W1T[67][64], W2T[64][64], W3T[64][128] ----------
__global__ __launch_bounds__(256) void k_wt(const float* __restrict__ W1, const float* __restrict__ W2,
    const float* __restrict__ W3, float* __restrict__ W1T, float* __restrict__ W2T, float* __restrict__ W3T){
  int t = blockIdx.x*256 + threadIdx.x;   // 32 blocks -> 8192 threads
  if (t < 67*64){ int c = t >> 6, o = t & 63;  W1T[t] = W1[o*67 + c]; }
  if (t < 64*64){ int c = t >> 6, o = t & 63;  W2T[t] = W2[o*64 + c]; }
  if (t < 64*128){ int c = t >> 7, o = t & 127; W3T[t] = W3[o*64 + c]; }
}

// ---------- features (B,64,N) fp32 -> featT (B,N,64) bf16 ----------
__global__ __launch_bounds__(256) void k_ft(const float* __restrict__ feat, unsigned short* __restrict__ featT){
  __shared__ float tile[64][65];
  const int b = blockIdx.x >> 6, n0 = (blockIdx.x & 63) << 6;
  const int t = threadIdx.x;
  const int nl = t & 63, cb = t >> 6;
  #pragma unroll
  for (int k=0;k<16;k++){
    int c = cb + (k<<2);
    tile[c][nl] = feat[((size_t)(b*64 + c))*NN + n0 + nl];
  }
  __syncthreads();
  #pragma unroll
  for (int k=0;k<16;k++){
    int nl2 = cb + (k<<2);
    featT[((size_t)(b*NN) + n0 + nl2)*64 + nl] = f2bf(tile[nl][nl2]);
  }
}

// ---------- row producers ----------
__device__ __forceinline__ void gather_y1(int r,
    const float* __restrict__ xyz, const unsigned short* __restrict__ featT,
    const float* __restrict__ nxyz, const int* __restrict__ ball_idx,
    const float* __restrict__ W1T, float* __restrict__ y)
{
  const int b = r >> 15;
  const int p = (r >> 5) & (NPOINTS-1);
  const int i = ball_idx[r];
  const int co = (b*NPOINTS + p)*3;
  const float* xp = xyz + ((size_t)(b*NN + i))*3;
  const float h0 = __fsub_rn(xp[0], nxyz[co]);
  const float h1 = __fsub_rn(xp[1], nxyz[co+1]);
  const float h2 = __fsub_rn(xp[2], nxyz[co+2]);
  #pragma unroll
  for (int o=0;o<64;o++) y[o] = h0 * W1T[o];
  #pragma unroll
  for (int o=0;o<64;o++) y[o] = fmaf(h1, W1T[64+o], y[o]);
  #pragma unroll
  for (int o=0;o<64;o++) y[o] = fmaf(h2, W1T[128+o], y[o]);
  const uint4* fp = (const uint4*)(featT + ((size_t)(b*NN + i))*64);
  #pragma unroll
  for (int c8=0;c8<8;c8++){
    const uint4 u = fp[c8];
    float fv[8];
    fv[0]=bflo(u.x); fv[1]=bfhi(u.x); fv[2]=bflo(u.y); fv[3]=bfhi(u.y);
    fv[4]=bflo(u.z); fv[5]=bfhi(u.z); fv[6]=bflo(u.w); fv[7]=bfhi(u.w);
    const float* wb = W1T + (3 + c8*8)*64;
    #pragma unroll
    for (int k=0;k<8;k++){
      #pragma unroll
      for (int o=0;o<64;o++) y[o] = fmaf(fv[k], wb[k*64+o], y[o]);
    }
  }
}

__device__ __forceinline__ void load_act(const unsigned short* __restrict__ act1, int r, float* __restrict__ y){
  const uint4* p = (const uint4*)(act1 + (size_t)r*64);
  #pragma unroll
  for (int j=0;j<8;j++){
    uint4 u = p[j];
    y[j*8+0]=bflo(u.x); y[j*8+1]=bfhi(u.x); y[j*8+2]=bflo(u.y); y[j*8+3]=bfhi(u.y);
    y[j*8+4]=bflo(u.z); y[j*8+5]=bfhi(u.z); y[j*8+6]=bflo(u.w); y[j*8+7]=bfhi(u.w);
  }
}

__device__ __forceinline__ void bnrelu64(float* __restrict__ y,
    const float* __restrict__ sc, const float* __restrict__ sh){
  #pragma unroll
  for (int o=0;o<64;o++) y[o] = fmaxf(0.f, fmaf(y[o], sc[o], sh[o]));
}

template<int LDW>
__device__ __forceinline__ void gemm64(const float* __restrict__ a, const float* __restrict__ WT,
                                       float* __restrict__ out){
  #pragma unroll
  for (int o=0;o<64;o++) out[o] = 0.f;
  #pragma unroll 4
  for (int c=0;c<64;c++){
    const float av = a[c];
    const float* wb = WT + c*LDW;    // wave-uniform -> s_load
    #pragma unroll
    for (int o=0;o<64;o++) out[o] = fmaf(av, wb[o], out[o]);
  }
}

// LDS transpose tile (stride 65: writes 2-way-free, column reads conflict-free)
__device__ __forceinline__ void stats_tile(float* tile, int t, const float* __restrict__ y,
                                           float& s, float& q){
  #pragma unroll
  for (int j=0;j<64;j++) tile[t*65 + j] = y[j];
  __syncthreads();
  #pragma unroll 8
  for (int r=0;r<64;r++){
    float v = tile[r*65 + t];
    s += v; q = fmaf(v, v, q);
  }
  __syncthreads();
}

// ---------- tier-1 only: gather -> y1 -> act1 (bf16) ----------
__global__ __launch_bounds__(256) void k_l1s(const float* __restrict__ xyz,
    const unsigned short* __restrict__ featT, const float* __restrict__ nxyz,
    const int* __restrict__ ball_idx, const float* __restrict__ W1T,
    unsigned short* __restrict__ act1){
  const int r = blockIdx.x*256 + threadIdx.x;
  float y[64];
  gather_y1(r, xyz, featT, nxyz, ball_idx, W1T, y);
  uint4* row = (uint4*)(act1 + (size_t)r*64);
  #pragma unroll
  for (int j=0;j<8;j++){
    union { uint4 u; unsigned short h[8]; } pk;
    #pragma unroll
    for (int k=0;k<8;k++) pk.h[k] = f2bf(y[j*8+k]);
    row[j] = pk.u;
  }
}

// ---------- fused stage kernels: recompute chain, per-channel sum/sumsq partials ----------
template<int STAGE, bool FROMACT>
__global__ __launch_bounds__(64) void k_stage(
    const float* __restrict__ xyz, const unsigned short* __restrict__ featT,
    const float* __restrict__ nxyz, const int* __restrict__ ball_idx,
    const unsigned short* __restrict__ act1,
    const float* __restrict__ W1T, const float* __restrict__ W2T, const float* __restrict__ W3T,
    const float* __restrict__ sc1, const float* __restrict__ sh1,
    const float* __restrict__ sc2, const float* __restrict__ sh2,
    float* __restrict__ partials)
{
  __shared__ float tile[64*65];
  const int t = threadIdx.x;
  float s0=0.f, q0=0.f, s1=0.f, q1=0.f;
  for (int it=0; it<RPB/64; ++it){
    const int r = blockIdx.x*RPB + it*64 + t;
    float y[64];
    if (FROMACT) load_act(act1, r, y);
    else         gather_y1(r, xyz, featT, nxyz, ball_idx, W1T, y);
    if (STAGE == 1){
      stats_tile(tile, t, y, s0, q0);
    } else {
      bnrelu64(y, sc1, sh1);                 // a1
      float y2[64];
      gemm64<64>(y, W2T, y2);                // y2
      if (STAGE == 2){
        stats_tile(tile, t, y2, s0, q0);
      } else {
        bnrelu64(y2, sc2, sh2);              // a2
        float y3[64];
        gemm64<128>(y2, W3T, y3);            // y3[0:64]
        stats_tile(tile, t, y3, s0, q0);
        gemm64<128>(y2, W3T + 64, y3);       // y3[64:128]
        stats_tile(tile, t, y3, s1, q1);
      }
    }
  }
  if (STAGE < 3){
    partials[(size_t)blockIdx.x*128 + t]      = s0;
    partials[(size_t)blockIdx.x*128 + 64 + t] = q0;
  } else {
    float* pb = partials + (size_t)blockIdx.x*256;
    pb[t] = s0; pb[64+t] = s1; pb[128+t] = q0; pb[192+t] = q1;
  }
}

// ---------- reduce partials -> BN scale/shift ----------
template<int C>
__global__ __launch_bounds__(256) void k_fin(const float* __restrict__ P, int nblk,
    const float* __restrict__ g, const float* __restrict__ bv,
    float* __restrict__ scale, float* __restrict__ shift)
{
  const int t = threadIdx.x;
  const int c = t & (C-1);
  const int gg = t / C;
  const int G = 256 / C;
  float S = 0.f, Q = 0.f;
  for (int i = gg; i < nblk; i += G){
    S += P[(size_t)i*2*C + c];
    Q += P[(size_t)i*2*C + C + c];
  }
  __shared__ float sS[256], sQ[256];
  sS[t] = S; sQ[t] = Q;
  __syncthreads();
  if (t < C){
    #pragma unroll
    for (int k=1;k<G;k++){ S += sS[k*C+c]; Q += sQ[k*C+c]; }
    float m  = S * (1.f/(float)MROWS);
    float vv = Q * (1.f/(float)MROWS) - m*m;
    float sc = g[c] / sqrtf(vv + EPSF);
    scale[c] = sc;
    shift[c] = bv[c] - m*sc;
  }
}

// ---------- final pass: chain -> y3 -> bn3+relu -> max over samples -> (B,128,1024) ----------
template<bool FROMACT>
__global__ __launch_bounds__(64) void k_pass2(
    const float* __restrict__ xyz, const unsigned short* __restrict__ featT,
    const float* __restrict__ nxyz, const int* __restrict__ ball_idx,
    const unsigned short* __restrict__ act1,
    const float* __restrict__ W1T, const float* __restrict__ W2T,
    const float* __restrict__ W3,
    const float* __restrict__ sc1, const float* __restrict__ sh1,
    const float* __restrict__ sc2, const float* __restrict__ sh2,
    const float* __restrict__ sc3, const float* __restrict__ sh3,
    float* __restrict__ out)
{
  const int t = threadIdx.x;
  const int s = t & 31;
  const int pair = blockIdx.x*2 + (t >> 5);   // (b,p)
  const int r = pair*32 + s;
  float y[64];
  if (FROMACT) load_act(act1, r, y);
  else         gather_y1(r, xyz, featT, nxyz, ball_idx, W1T, y);
  bnrelu64(y, sc1, sh1);
  float a2[64];
  gemm64<64>(y, W2T, a2);
  bnrelu64(a2, sc2, sh2);
  const int b = pair >> 10, p = pair & (NPOINTS-1);
  float* ob = out + OUT2_OFF + ((size_t)b*128)*1024 + p;
  for (int o=0;o<128;o++){
    const float* wr = W3 + o*64;               // wave-uniform -> s_load
    float v = 0.f;
    #pragma unroll
    for (int c=0;c<64;c++) v = fmaf(a2[c], wr[c], v);
    v = fmaxf(0.f, fmaf(v, sc3[o], sh3[o]));
    #pragma unroll
    for (int off=16; off>=1; off>>=1) v = fmaxf(v, __shfl_xor(v, off, 64));
    if (s == 0) ob[(size_t)o*1024] = v;
  }
}

extern "C" void kernel_launch(void* const* d_in, const int* in_sizes, int n_in,
                              void* d_out, int out_size, void* d_ws, size_t ws_size,
                              hipStream_t stream) {
  const float* xyz  = (const float*)d_in[0];
  const float* feat = (const float*)d_in[1];
  const float* W1   = (const float*)d_in[2];
  const float* g1   = (const float*)d_in[3];
  const float* b1   = (const float*)d_in[4];
  const float* W2   = (const float*)d_in[5];
  const float* g2   = (const float*)d_in[6];
  const float* b2   = (const float*)d_in[7];
  const float* W3   = (const float*)d_in[8];
  const float* g3   = (const float*)d_in[9];
  const float* b3   = (const float*)d_in[10];
  float* out = (float*)d_out;
  char* ws = (char*)d_ws;

  // workspace layout (compact): ~15.0 MB; +64 MB act1 for tier-1
  const size_t o_nxyz = 0;                    // 49152 f
  const size_t o_ball = o_nxyz + 196608;      // 524288 i
  const size_t o_w1t  = o_ball + 2097152;     // 4288 f (pad)
  const size_t o_w2t  = o_w1t  + 17408;       // 4096 f
  const size_t o_w3t  = o_w2t  + 16384;       // 8192 f
  const size_t o_bn   = o_w3t  + 32768;       // 6 x 512B
  const size_t o_p    = o_bn   + 3072;        // NBLK*256 f = 4 MB
  const size_t o_ft   = o_p    + (size_t)NBLK*256*4;         // 8 MB bf16
  const size_t o_act1 = o_ft   + (size_t)16*NN*64*2;         // 64 MB bf16
  const size_t NEED1  = o_act1 + (size_t)MROWS*64*2;

  float* nxyz   = (float*)(ws + o_nxyz);
  int*   ball   = (int*)  (ws + o_ball);
  float* W1T    = (float*)(ws + o_w1t);
  float* W2T    = (float*)(ws + o_w2t);
  float* W3T    = (float*)(ws + o_w3t);
  float* sc1    = (float*)(ws + o_bn);
  float* sh1    = (float*)(ws + o_bn + 512);
  float* sc2    = (float*)(ws + o_bn + 1024);
  float* sh2    = (float*)(ws + o_bn + 1536);
  float* sc3    = (float*)(ws + o_bn + 2048);
  float* sh3    = (float*)(ws + o_bn + 2560);
  float* part   = (float*)(ws + o_p);
  unsigned short* featT = (unsigned short*)(ws + o_ft);
  unsigned short* act1  = (unsigned short*)(ws + o_act1);

  const bool tier1 = (ws_size >= NEED1);

  k_wt  <<<32,   256, 0, stream>>>(W1, W2, W3, W1T, W2T, W3T);
  k_ft  <<<1024, 256, 0, stream>>>(feat, featT);
  k_fps <<<16,   512, 0, stream>>>(xyz, nxyz, out);
  k_ball<<<64,   256, 0, stream>>>(xyz, nxyz, ball);

  if (tier1){
    k_l1s<<<2048, 256, 0, stream>>>(xyz, featT, nxyz, ball, W1T, act1);
    k_stage<1,true><<<NBLK, 64, 0, stream>>>(xyz, featT, nxyz, ball, act1, W1T, W2T, W3T,
                                             sc1, sh1, sc2, sh2, part);
    k_fin<64><<<1, 256, 0, stream>>>(part, NBLK, g1, b1, sc1, sh1);
    k_stage<2,true><<<NBLK, 64, 0, stream>>>(xyz, featT, nxyz, ball, act1, W1T, W2T, W3T,
                                             sc1, sh1, sc2, sh2, part);
    k_fin<64><<<1, 256, 0, stream>>>(part, NBLK, g2, b2, sc2, sh2);
    k_stage<3,true><<<NBLK, 64, 0, stream>>>(xyz, featT, nxyz, ball, act1, W1T, W2T, W3T,
                                             sc1, sh1, sc2, sh2, part);
    k_fin<128><<<1, 256, 0, stream>>>(part, NBLK, g3, b3, sc3, sh3);
    k_pass2<true><<<8192, 64, 0, stream>>>(xyz, featT, nxyz, ball, act1, W1T, W2T, W3,
                                           sc1, sh1, sc2, sh2, sc3, sh3, out);
  } else {
    k_stage<1,false><<<NBLK, 64, 0, stream>>>(xyz, featT, nxyz, ball, act1, W1T, W2T, W3T,
                                              sc1, sh1, sc2, sh2, part);
    k_fin<64><<<1, 256, 0, stream>>>(part, NBLK, g1, b1, sc1, sh1);
    k_stage<2,false><<<NBLK, 64, 0, stream>>>(xyz, featT, nxyz, ball, act1, W1T, W2T, W3T,
                                              sc1, sh1, sc2, sh2, part);
    k_fin<64><<<1, 256, 0, stream>>>(part, NBLK, g2, b2, sc2, sh2);
    k_stage<3,false><<<NBLK, 64, 0, stream>>>(xyz, featT, nxyz, ball, act1, W1T, W2T, W3T,
                                              sc1, sh1, sc2, sh2, part);
    k_fin<128><<<1, 256, 0, stream>>>(part, NBLK, g3, b3, sc3, sh3);
    k_pass2<false><<<8192, 64, 0, stream>>>(xyz, featT, nxyz, ball, act1, W1T, W2T, W3,
                                            sc1, sh1, sc2, sh2, sc3, sh3, out);
  }
}

// Round 3
// 2499.393 us; speedup vs baseline: 1.5122x; 1.5122x over previous
//
#include <hip/hip_runtime.h>

#define NN 4096
#define NPOINTS 1024
#define NSAMP 32
#define MROWS (16*NPOINTS*NSAMP)      // 524288
#define OUT2_OFF (16*NPOINTS*3)       // 49152
#define EPSF 1e-5f
#define RPB 128                       // rows per stats block
#define NBLK 4096                     // stats blocks (NBLK*RPB == MROWS)

// ---------- bf16 helpers ----------
__device__ __forceinline__ float bflo(unsigned int u){ union{unsigned int i; float f;} v; v.i = u << 16; return v.f; }
__device__ __forceinline__ float bfhi(unsigned int u){ union{unsigned int i; float f;} v; v.i = u & 0xffff0000u; return v.f; }
__device__ __forceinline__ unsigned short f2bf(float f){
  union{float f; unsigned int i;} v; v.f = f;
  unsigned int r = v.i + 0x7fffu + ((v.i >> 16) & 1u);
  return (unsigned short)(r >> 16);
}

// ---------- FPS: packed u64 argmax, single barrier per iteration ----------
// key = (float_bits(d) << 32) | ~idx : d>=0 so bits are order-monotone;
// u64 max == (max d, tie -> min idx) == jnp.argmax first-occurrence.
__global__ __launch_bounds__(512) void k_fps(const float* __restrict__ xyz,
    float* __restrict__ nxyz, float* __restrict__ out){
  __shared__ float xs[NN], ys[NN], zs[NN];
  __shared__ unsigned long long wbest[2][8];
  const int b = blockIdx.x, t = threadIdx.x;
  const float* xb = xyz + (size_t)b*NN*3;
  for (int j = t; j < NN; j += 512){
    xs[j] = xb[j*3+0]; ys[j] = xb[j*3+1]; zs[j] = xb[j*3+2];
  }
  __syncthreads();
  float px[8], py[8], pz[8], pd[8];
  #pragma unroll
  for (int j=0;j<8;j++){ int i=j*512+t; px[j]=xs[i]; py[j]=ys[i]; pz[j]=zs[i]; pd[j]=1e10f; }
  int cur = 0;
  const int lane = t & 63, wv = t >> 6;
  for (int it=0; it<NPOINTS; ++it){
    float lx = xs[cur], ly = ys[cur], lz = zs[cur];
    if (t == 0){
      int o = (b*NPOINTS + it)*3;
      nxyz[o]=lx; nxyz[o+1]=ly; nxyz[o+2]=lz;
      out[o]=lx;  out[o+1]=ly;  out[o+2]=lz;
    }
    float bv = -1.0f; int bi = 0;
    #pragma unroll
    for (int j=0;j<8;j++){
      float dx = __fsub_rn(px[j], lx);
      float dy = __fsub_rn(py[j], ly);
      float dz = __fsub_rn(pz[j], lz);
      float d  = __fadd_rn(__fadd_rn(__fmul_rn(dx,dx), __fmul_rn(dy,dy)), __fmul_rn(dz,dz));
      float nd = fminf(pd[j], d);
      pd[j] = nd;
      if (nd > bv){ bv = nd; bi = j*512 + t; }   // strict > : first occurrence within thread
    }
    unsigned long long key = ((unsigned long long)__float_as_uint(bv) << 32)
                           | (unsigned long long)(0xFFFFFFFFu - (unsigned)bi);
    #pragma unroll
    for (int off=32; off>=1; off>>=1){
      unsigned long long ok = __shfl_xor(key, off, 64);
      if (ok > key) key = ok;
    }
    if (lane == 0) wbest[it & 1][wv] = key;
    __syncthreads();
    unsigned long long best = wbest[it & 1][0];
    #pragma unroll
    for (int w=1; w<8; w++){
      unsigned long long ok = wbest[it & 1][w];
      if (ok > best) best = ok;
    }
    cur = (int)(0xFFFFFFFFu - (unsigned)(best & 0xFFFFFFFFull));
    // parity double-buffer: slot (it&1) not rewritten until after next barrier -> safe
  }
}

// ---------- Ball query: first-32 in-ball indices; R2 = f32(0.04) exactly ----------
__global__ __launch_bounds__(64) void k_ball(const float* __restrict__ xyz,
    const float* __restrict__ nxyz, int* __restrict__ ball_idx){
  const int g = blockIdx.x;           // 256 blocks x 64 threads
  const int b = g >> 4;
  const int p = ((g & 15) << 6) + threadIdx.x;
  const float* xb = xyz + (size_t)b*NN*3;
  const int co = (b*NPOINTS + p)*3;
  const float cx = nxyz[co], cy = nxyz[co+1], cz = nxyz[co+2];
  const int base = (b*NPOINTS + p)*NSAMP;
  const float R2 = 0.04f;
  int cnt = 0, first = 0;
  for (int i = 0; i < NN; ++i){
    float lx = xb[i*3+0], ly = xb[i*3+1], lz = xb[i*3+2];   // wave-uniform -> s_load
    float dx = __fsub_rn(cx, lx);
    float dy = __fsub_rn(cy, ly);
    float dz = __fsub_rn(cz, lz);
    float d2 = __fadd_rn(__fadd_rn(__fmul_rn(dx,dx), __fmul_rn(dy,dy)), __fmul_rn(dz,dz));
    if (d2 < R2 && cnt < NSAMP){
      ball_idx[base + cnt] = i;
      if (cnt == 0) first = i;
      cnt++;
    }
    if ((i & 255) == 255){
      if (__ballot(cnt < NSAMP) == 0ULL) break;
    }
  }
  for (int k = cnt; k < NSAMP; ++k) ball_idx[base + k] = first;
}

// ---------- weight transposes: W1T[67][64], W2T[64][64], W3T[64][128] ----------
__global__ __launch_bounds__(256) void k_wt(const float* __restrict__ W1, const float* __restrict__ W2,
    const float* __restrict__ W3, float* __restrict__ W1T, float* __restrict__ W2T, float* __restrict__ W3T){
  int t = blockIdx.x*256 + threadIdx.x;   // 32 blocks -> 8192 threads
  if (t < 67*64){ int c = t >> 6, o = t & 63;  W1T[t] = W1[o*67 + c]; }
  if (t < 64*64){ int c = t >> 6, o = t & 63;  W2T[t] = W2[o*64 + c]; }
  if (t < 64*128){ int c = t >> 7, o = t & 127; W3T[t] = W3[o*64 + c]; }
}

// ---------- features (B,64,N) fp32 -> featT (B,N,64) bf16 ----------
__global__ __launch_bounds__(256) void k_ft(const float* __restrict__ feat, unsigned short* __restrict__ featT){
  __shared__ float tile[64][65];
  const int b = blockIdx.x >> 6, n0 = (blockIdx.x & 63) << 6;
  const int t = threadIdx.x;
  const int nl = t & 63, cb = t >> 6;
  #pragma unroll
  for (int k=0;k<16;k++){
    int c = cb + (k<<2);
    tile[c][nl] = feat[((size_t)(b*64 + c))*NN + n0 + nl];
  }
  __syncthreads();
  #pragma unroll
  for (int k=0;k<16;k++){
    int nl2 = cb + (k<<2);
    featT[((size_t)(b*NN) + n0 + nl2)*64 + nl] = f2bf(tile[nl][nl2]);
  }
}

// ---------- row producers ----------
__device__ __forceinline__ void gather_y1(int r,
    const float* __restrict__ xyz, const unsigned short* __restrict__ featT,
    const float* __restrict__ nxyz, const int* __restrict__ ball_idx,
    const float* __restrict__ W1T, float* __restrict__ y)
{
  const int b = r >> 15;
  const int p = (r >> 5) & (NPOINTS-1);
  const int i = ball_idx[r];
  const int co = (b*NPOINTS + p)*3;
  const float* xp = xyz + ((size_t)(b*NN + i))*3;
  const float h0 = __fsub_rn(xp[0], nxyz[co]);
  const float h1 = __fsub_rn(xp[1], nxyz[co+1]);
  const float h2 = __fsub_rn(xp[2], nxyz[co+2]);
  #pragma unroll
  for (int o=0;o<64;o++) y[o] = h0 * W1T[o];
  #pragma unroll
  for (int o=0;o<64;o++) y[o] = fmaf(h1, W1T[64+o], y[o]);
  #pragma unroll
  for (int o=0;o<64;o++) y[o] = fmaf(h2, W1T[128+o], y[o]);
  const uint4* fp = (const uint4*)(featT + ((size_t)(b*NN + i))*64);
  #pragma unroll
  for (int c8=0;c8<8;c8++){
    const uint4 u = fp[c8];
    float fv[8];
    fv[0]=bflo(u.x); fv[1]=bfhi(u.x); fv[2]=bflo(u.y); fv[3]=bfhi(u.y);
    fv[4]=bflo(u.z); fv[5]=bfhi(u.z); fv[6]=bflo(u.w); fv[7]=bfhi(u.w);
    const float* wb = W1T + (3 + c8*8)*64;
    #pragma unroll
    for (int k=0;k<8;k++){
      #pragma unroll
      for (int o=0;o<64;o++) y[o] = fmaf(fv[k], wb[k*64+o], y[o]);
    }
  }
}

__device__ __forceinline__ void load_act(const unsigned short* __restrict__ act1, int r, float* __restrict__ y){
  const uint4* p = (const uint4*)(act1 + (size_t)r*64);
  #pragma unroll
  for (int j=0;j<8;j++){
    uint4 u = p[j];
    y[j*8+0]=bflo(u.x); y[j*8+1]=bfhi(u.x); y[j*8+2]=bflo(u.y); y[j*8+3]=bfhi(u.y);
    y[j*8+4]=bflo(u.z); y[j*8+5]=bfhi(u.z); y[j*8+6]=bflo(u.w); y[j*8+7]=bfhi(u.w);
  }
}

__device__ __forceinline__ void bnrelu64(float* __restrict__ y,
    const float* __restrict__ sc, const float* __restrict__ sh){
  #pragma unroll
  for (int o=0;o<64;o++) y[o] = fmaxf(0.f, fmaf(y[o], sc[o], sh[o]));
}

template<int LDW>
__device__ __forceinline__ void gemm64(const float* __restrict__ a, const float* __restrict__ WT,
                                       float* __restrict__ out){
  #pragma unroll
  for (int o=0;o<64;o++) out[o] = 0.f;
  #pragma unroll 4
  for (int c=0;c<64;c++){
    const float av = a[c];
    const float* wb = WT + c*LDW;    // wave-uniform -> s_load
    #pragma unroll
    for (int o=0;o<64;o++) out[o] = fmaf(av, wb[o], out[o]);
  }
}

// LDS transpose tile (stride 65: writes 2-way-free, column reads conflict-free)
__device__ __forceinline__ void stats_tile(float* tile, int t, const float* __restrict__ y,
                                           float& s, float& q){
  #pragma unroll
  for (int j=0;j<64;j++) tile[t*65 + j] = y[j];
  __syncthreads();
  #pragma unroll 8
  for (int r=0;r<64;r++){
    float v = tile[r*65 + t];
    s += v; q = fmaf(v, v, q);
  }
  __syncthreads();
}

// ---------- tier-1 only: gather -> y1 -> act1 (bf16) ----------
__global__ __launch_bounds__(256) void k_l1s(const float* __restrict__ xyz,
    const unsigned short* __restrict__ featT, const float* __restrict__ nxyz,
    const int* __restrict__ ball_idx, const float* __restrict__ W1T,
    unsigned short* __restrict__ act1){
  const int r = blockIdx.x*256 + threadIdx.x;
  float y[64];
  gather_y1(r, xyz, featT, nxyz, ball_idx, W1T, y);
  uint4* row = (uint4*)(act1 + (size_t)r*64);
  #pragma unroll
  for (int j=0;j<8;j++){
    union { uint4 u; unsigned short h[8]; } pk;
    #pragma unroll
    for (int k=0;k<8;k++) pk.h[k] = f2bf(y[j*8+k]);
    row[j] = pk.u;
  }
}

// ---------- fused stage kernels: recompute chain, atomic per-channel sum/sumsq ----------
template<int STAGE, bool FROMACT>
__global__ __launch_bounds__(64) void k_stage(
    const float* __restrict__ xyz, const unsigned short* __restrict__ featT,
    const float* __restrict__ nxyz, const int* __restrict__ ball_idx,
    const unsigned short* __restrict__ act1,
    const float* __restrict__ W1T, const float* __restrict__ W2T, const float* __restrict__ W3T,
    const float* __restrict__ sc1, const float* __restrict__ sh1,
    const float* __restrict__ sc2, const float* __restrict__ sh2,
    float* __restrict__ sums)
{
  __shared__ float tile[64*65];
  const int t = threadIdx.x;
  float s0=0.f, q0=0.f, s1=0.f, q1=0.f;
  for (int it=0; it<RPB/64; ++it){
    const int r = blockIdx.x*RPB + it*64 + t;
    float y[64];
    if (FROMACT) load_act(act1, r, y);
    else         gather_y1(r, xyz, featT, nxyz, ball_idx, W1T, y);
    if (STAGE == 1){
      stats_tile(tile, t, y, s0, q0);
    } else {
      bnrelu64(y, sc1, sh1);                 // a1
      float y2[64];
      gemm64<64>(y, W2T, y2);                // y2
      if (STAGE == 2){
        stats_tile(tile, t, y2, s0, q0);
      } else {
        bnrelu64(y2, sc2, sh2);              // a2
        float y3[64];
        gemm64<128>(y2, W3T, y3);            // y3[0:64]
        stats_tile(tile, t, y3, s0, q0);
        gemm64<128>(y2, W3T + 64, y3);       // y3[64:128]
        stats_tile(tile, t, y3, s1, q1);
      }
    }
  }
  if (STAGE < 3){
    atomicAdd(&sums[t], s0);
    atomicAdd(&sums[64 + t], q0);
  } else {
    atomicAdd(&sums[t], s0);        // ch t sum
    atomicAdd(&sums[64 + t], s1);   // ch 64+t sum
    atomicAdd(&sums[128 + t], q0);  // ch t sumsq
    atomicAdd(&sums[192 + t], q1);  // ch 64+t sumsq
  }
}

// ---------- finalize BN scale/shift from accumulated sums ----------
template<int C>
__global__ void k_fin(const float* __restrict__ sums,
    const float* __restrict__ g, const float* __restrict__ bv,
    float* __restrict__ scale, float* __restrict__ shift)
{
  const int c = threadIdx.x;   // C threads
  float m  = sums[c]   * (1.f/(float)MROWS);
  float vv = sums[C+c] * (1.f/(float)MROWS) - m*m;
  float sc = g[c] / sqrtf(vv + EPSF);
  scale[c] = sc;
  shift[c] = bv[c] - m*sc;
}

// ---------- final pass: chain -> y3 -> bn3+relu -> max over samples -> (B,128,1024) ----------
template<bool FROMACT>
__global__ __launch_bounds__(64) void k_pass2(
    const float* __restrict__ xyz, const unsigned short* __restrict__ featT,
    const float* __restrict__ nxyz, const int* __restrict__ ball_idx,
    const unsigned short* __restrict__ act1,
    const float* __restrict__ W1T, const float* __restrict__ W2T,
    const float* __restrict__ W3,
    const float* __restrict__ sc1, const float* __restrict__ sh1,
    const float* __restrict__ sc2, const float* __restrict__ sh2,
    const float* __restrict__ sc3, const float* __restrict__ sh3,
    float* __restrict__ out)
{
  const int t = threadIdx.x;
  const int s = t & 31;
  const int pair = blockIdx.x*2 + (t >> 5);   // (b,p)
  const int r = pair*32 + s;
  float y[64];
  if (FROMACT) load_act(act1, r, y);
  else         gather_y1(r, xyz, featT, nxyz, ball_idx, W1T, y);
  bnrelu64(y, sc1, sh1);
  float a2[64];
  gemm64<64>(y, W2T, a2);
  bnrelu64(a2, sc2, sh2);
  const int b = pair >> 10, p = pair & (NPOINTS-1);
  float* ob = out + OUT2_OFF + ((size_t)b*128)*1024 + p;
  for (int o=0;o<128;o++){
    const float* wr = W3 + o*64;               // wave-uniform -> s_load
    float v = 0.f;
    #pragma unroll
    for (int c=0;c<64;c++) v = fmaf(a2[c], wr[c], v);
    v = fmaxf(0.f, fmaf(v, sc3[o], sh3[o]));
    #pragma unroll
    for (int off=16; off>=1; off>>=1) v = fmaxf(v, __shfl_xor(v, off, 64));
    if (s == 0) ob[(size_t)o*1024] = v;
  }
}

extern "C" void kernel_launch(void* const* d_in, const int* in_sizes, int n_in,
                              void* d_out, int out_size, void* d_ws, size_t ws_size,
                              hipStream_t stream) {
  const float* xyz  = (const float*)d_in[0];
  const float* feat = (const float*)d_in[1];
  const float* W1   = (const float*)d_in[2];
  const float* g1   = (const float*)d_in[3];
  const float* b1   = (const float*)d_in[4];
  const float* W2   = (const float*)d_in[5];
  const float* g2   = (const float*)d_in[6];
  const float* b2   = (const float*)d_in[7];
  const float* W3   = (const float*)d_in[8];
  const float* g3   = (const float*)d_in[9];
  const float* b3   = (const float*)d_in[10];
  float* out = (float*)d_out;
  char* ws = (char*)d_ws;

  // workspace layout: ~10.8 MB base; +67 MB act1 for tier-1
  const size_t o_nxyz = 0;                    // 49152 f
  const size_t o_ball = o_nxyz + 196608;      // 524288 i
  const size_t o_w1t  = o_ball + 2097152;     // 4288 f (pad)
  const size_t o_w2t  = o_w1t  + 17408;       // 4096 f
  const size_t o_w3t  = o_w2t  + 16384;       // 8192 f
  const size_t o_bn   = o_w3t  + 32768;       // 6 x 512B
  const size_t o_sum  = o_bn   + 3072;        // sums1(512) sums2(512) sums3(1024)
  const size_t o_ft   = o_sum  + 2048;        // 8 MB bf16 (16B aligned)
  const size_t o_act1 = o_ft   + (size_t)16*NN*64*2;
  const size_t NEED1  = o_act1 + (size_t)MROWS*64*2;

  float* nxyz   = (float*)(ws + o_nxyz);
  int*   ball   = (int*)  (ws + o_ball);
  float* W1T    = (float*)(ws + o_w1t);
  float* W2T    = (float*)(ws + o_w2t);
  float* W3T    = (float*)(ws + o_w3t);
  float* sc1    = (float*)(ws + o_bn);
  float* sh1    = (float*)(ws + o_bn + 512);
  float* sc2    = (float*)(ws + o_bn + 1024);
  float* sh2    = (float*)(ws + o_bn + 1536);
  float* sc3    = (float*)(ws + o_bn + 2048);
  float* sh3    = (float*)(ws + o_bn + 2560);
  float* sums1  = (float*)(ws + o_sum);
  float* sums2  = (float*)(ws + o_sum + 512);
  float* sums3  = (float*)(ws + o_sum + 1024);
  unsigned short* featT = (unsigned short*)(ws + o_ft);
  unsigned short* act1  = (unsigned short*)(ws + o_act1);

  const bool tier1 = (ws_size >= NEED1);

  hipMemsetAsync(ws + o_sum, 0, 2048, stream);

  k_wt  <<<32,   256, 0, stream>>>(W1, W2, W3, W1T, W2T, W3T);
  k_ft  <<<1024, 256, 0, stream>>>(feat, featT);
  k_fps <<<16,   512, 0, stream>>>(xyz, nxyz, out);
  k_ball<<<256,  64,  0, stream>>>(xyz, nxyz, ball);

  if (tier1){
    k_l1s<<<2048, 256, 0, stream>>>(xyz, featT, nxyz, ball, W1T, act1);
    k_stage<1,true><<<NBLK, 64, 0, stream>>>(xyz, featT, nxyz, ball, act1, W1T, W2T, W3T,
                                             sc1, sh1, sc2, sh2, sums1);
    k_fin<64><<<1, 64, 0, stream>>>(sums1, g1, b1, sc1, sh1);
    k_stage<2,true><<<NBLK, 64, 0, stream>>>(xyz, featT, nxyz, ball, act1, W1T, W2T, W3T,
                                             sc1, sh1, sc2, sh2, sums2);
    k_fin<64><<<1, 64, 0, stream>>>(sums2, g2, b2, sc2, sh2);
    k_stage<3,true><<<NBLK, 64, 0, stream>>>(xyz, featT, nxyz, ball, act1, W1T, W2T, W3T,
                                             sc1, sh1, sc2, sh2, sums3);
    k_fin<128><<<1, 128, 0, stream>>>(sums3, g3, b3, sc3, sh3);
    k_pass2<true><<<8192, 64, 0, stream>>>(xyz, featT, nxyz, ball, act1, W1T, W2T, W3,
                                           sc1, sh1, sc2, sh2, sc3, sh3, out);
  } else {
    k_stage<1,false><<<NBLK, 64, 0, stream>>>(xyz, featT, nxyz, ball, act1, W1T, W2T, W3T,
                                              sc1, sh1, sc2, sh2, sums1);
    k_fin<64><<<1, 64, 0, stream>>>(sums1, g1, b1, sc1, sh1);
    k_stage<2,false><<<NBLK, 64, 0, stream>>>(xyz, featT, nxyz, ball, act1, W1T, W2T, W3T,
                                              sc1, sh1, sc2, sh2, sums2);
    k_fin<64><<<1, 64, 0, stream>>>(sums2, g2, b2, sc2, sh2);
    k_stage<3,false><<<NBLK, 64, 0, stream>>>(xyz, featT, nxyz, ball, act1, W1T, W2T, W3T,
                                              sc1, sh1, sc2, sh2, sums3);
    k_fin<128><<<1, 128, 0, stream>>>(sums3, g3, b3, sc3, sh3);
    k_pass2<false><<<8192, 64, 0, stream>>>(xyz, featT, nxyz, ball, act1, W1T, W2T, W3,
                                            sc1, sh1, sc2, sh2, sc3, sh3, out);
  }
}